// Round 12
// baseline (527.094 us; speedup 1.0000x reference)
//
#include <hip/hip_runtime.h>
#include <hip/hip_bf16.h>

#define S_DIM 128
#define B_DIM 4
#define L_DIM (S_DIM * S_DIM)   // 16384 per batch

typedef __bf16 bf16x8 __attribute__((ext_vector_type(8)));
typedef float f32x4 __attribute__((ext_vector_type(4)));

__device__ __forceinline__ float b2f(unsigned short u) {
    union { unsigned int i; float f; } v;
    v.i = ((unsigned int)u) << 16;
    return v.f;
}
__device__ __forceinline__ unsigned short f2b(float f) {
    union { float f; unsigned int i; } v;
    v.f = f;
    unsigned int x = v.i;
    return (unsigned short)((x + 0x7FFFu + ((x >> 16) & 1u)) >> 16);
}
__device__ __forceinline__ float ldx(const void* p, size_t i, int f32) {
    return f32 ? ((const float*)p)[i] : b2f(((const unsigned short*)p)[i]);
}
// async global->LDS, 16B per lane; lds dest must be wave-uniform base
__device__ __forceinline__ void gload16(const unsigned short* g, unsigned short* l) {
    __builtin_amdgcn_global_load_lds(
        (const __attribute__((address_space(1))) unsigned int*)g,
        (__attribute__((address_space(3))) unsigned int*)l, 16, 0, 0);
}

// ---------------------------------------------------------------------------
__global__ __launch_bounds__(256) void sniff_dtype(const unsigned short* __restrict__ x,
                                                   int* __restrict__ flag) {
    __shared__ int cnt;
    if (threadIdx.x == 0) cnt = 0;
    __syncthreads();
    int c = 0;
    for (int i = threadIdx.x; i < 32768; i += 256) {
        unsigned int e = (x[i] >> 7) & 0xFFu;
        if (e >= 0x91u) c++;
    }
    atomicAdd(&cnt, c);
    __syncthreads();
    if (threadIdx.x == 0) flag[0] = (cnt > 64) ? 1 : 0;
}

// ---------------------------------------------------------------------------
__global__ void transpose_any(const void* __restrict__ src,
                              unsigned short* __restrict__ dst, int R, int C,
                              const int* __restrict__ flag) {
    const int f = flag[0];
    int idx = blockIdx.x * 256 + threadIdx.x;
    if (idx >= R * C) return;
    int r = idx / C, c = idx - r * C;
    dst[c * R + r] = f2b(ldx(src, idx, f));
}

// ---------------------------------------------------------------------------
// Cast x (f32 or bf16, per flag) to bf16. Vector 8-wide, grid-stride.
// ---------------------------------------------------------------------------
__global__ __launch_bounds__(256) void cast_to_bf16(
    const void* __restrict__ src, size_t s_off,
    unsigned short* __restrict__ dst, size_t n,
    const int* __restrict__ flag)
{
    const int f = flag[0];
    size_t idx = ((size_t)blockIdx.x * 256 + threadIdx.x) * 8;
    const size_t stride = (size_t)gridDim.x * 256 * 8;
    for (; idx < n; idx += stride) {
        if (f) {
            const float4* s4 = (const float4*)((const float*)src + s_off + idx);
            float4 a = s4[0], b = s4[1];
            uint4 w;
            w.x = (unsigned int)f2b(a.x) | ((unsigned int)f2b(a.y) << 16);
            w.y = (unsigned int)f2b(a.z) | ((unsigned int)f2b(a.w) << 16);
            w.z = (unsigned int)f2b(b.x) | ((unsigned int)f2b(b.y) << 16);
            w.w = (unsigned int)f2b(b.z) | ((unsigned int)f2b(b.w) << 16);
            *(uint4*)(dst + idx) = w;
        } else {
            *(uint4*)(dst + idx) =
                *(const uint4*)((const unsigned short*)src + s_off + idx);
        }
    }
}

// ---------------------------------------------------------------------------
// Implicit filter MLP: one block per s. out [s][d] f32 (includes decay).
// ---------------------------------------------------------------------------
__global__ __launch_bounds__(256) void filter_mlp(
    const void* __restrict__ freq,
    const void* __restrict__ w0, const void* __restrict__ b0,
    const void* __restrict__ w1, const void* __restrict__ b1,
    const void* __restrict__ w2, const void* __restrict__ b2,
    const void* __restrict__ w3,
    float* __restrict__ out, const int* __restrict__ flag)
{
    __shared__ float hs[64], gs[64];
    const int f32f = flag[0];
    const int s   = blockIdx.x;
    const int tid = threadIdx.x;
    const float t = (float)s / (float)(S_DIM - 1);
    const float ang = 1e-4f * 2.0f * 3.14159265358979323846f * ((float)s / (float)S_DIM);
    const float z0 = t, z1 = cosf(ang), z2 = -sinf(ang);

    if (tid < 64) {
        float fr = ldx(freq, tid, f32f);
        float a = z0 * ldx(w0, 0 * 64 + tid, f32f) + z1 * ldx(w0, 1 * 64 + tid, f32f) +
                  z2 * ldx(w0, 2 * 64 + tid, f32f) + ldx(b0, tid, f32f);
        hs[tid] = sinf(fr * a);
    }
    __syncthreads();
    if (tid < 64) {
        float fr = ldx(freq, tid, f32f);
        float a = ldx(b1, tid, f32f);
        for (int e = 0; e < 64; e++) a += hs[e] * ldx(w1, e * 64 + tid, f32f);
        gs[tid] = sinf(fr * a);
    }
    __syncthreads();
    if (tid < 64) {
        float fr = ldx(freq, tid, f32f);
        float a = ldx(b2, tid, f32f);
        for (int e = 0; e < 64; e++) a += gs[e] * ldx(w2, e * 64 + tid, f32f);
        hs[tid] = sinf(fr * a);
    }
    __syncthreads();
    {
        const float min_d = -3.0701134573253943f;   // ln(0.01)/1.5
        const float max_d = -15.350567286626971f;   // ln(0.01)/0.3
        float a = 0.f;
        for (int e = 0; e < 64; e++) a += hs[e] * ldx(w3, e * 256 + tid, f32f);
        float delta = min_d + (max_d - min_d) * ((float)tid / 255.0f);
        float dec = expf(-t * fabsf(delta));
        out[s * 256 + tid] = a * dec;
    }
}

// ---------------------------------------------------------------------------
// GEMM v2 (m97-style): C[M][N] = A[M][K]*BT[N][K]^T + bias[N], A/BT bf16.
// Linear LDS [128][32]; staging via global_load_lds width 16 (see r9 notes).
// ---------------------------------------------------------------------------
__global__ __launch_bounds__(256) void gemm_bt16(
    const unsigned short* __restrict__ A,
    const unsigned short* __restrict__ BT,
    const void* __restrict__ bias, int bias_ext,
    void* __restrict__ C, size_t c_off, int c_ext,
    int M, int N, int K, const int* __restrict__ flag)
{
    __shared__ __align__(16) unsigned short As[128 * 32];
    __shared__ __align__(16) unsigned short Bs[128 * 32];

    const int f     = flag[0];
    const int b_f32 = bias_ext && f;
    const int c_f32 = c_ext && f;

    const int tid  = threadIdx.x;
    const int m0   = blockIdx.x * 128;
    const int n0   = blockIdx.y * 128;
    const int wid  = tid >> 6;
    const int lane = tid & 63;
    const int lrow = lane & 15;
    const int quad = lane >> 4;
    const int wr   = wid >> 1, wc = wid & 1;

    const int srow = lane >> 2;
    const int scol = (lane & 3) * 8;

    f32x4 acc[4][4];
#pragma unroll
    for (int a = 0; a < 4; a++)
#pragma unroll
        for (int b = 0; b < 4; b++)
#pragma unroll
            for (int r = 0; r < 4; r++) acc[a][b][r] = 0.0f;

    for (int kc = 0; kc < K; kc += 32) {
#pragma unroll
        for (int c = 0; c < 2; c++) {
            const int ch  = wid * 2 + c;          // 0..7, wave-uniform
            const int row = ch * 16 + srow;
            gload16(A  + (size_t)(m0 + row) * K + kc + scol, &As[ch * 512]);
            gload16(BT + (size_t)(n0 + row) * K + kc + scol, &Bs[ch * 512]);
        }
        __syncthreads();

        bf16x8 af[4], bfr[4];
#pragma unroll
        for (int fm = 0; fm < 4; fm++)
            af[fm] = *(const bf16x8*)(&As[(wr * 64 + fm * 16 + lrow) * 32 + quad * 8]);
#pragma unroll
        for (int fn = 0; fn < 4; fn++)
            bfr[fn] = *(const bf16x8*)(&Bs[(wc * 64 + fn * 16 + lrow) * 32 + quad * 8]);
#pragma unroll
        for (int fm = 0; fm < 4; fm++)
#pragma unroll
            for (int fn = 0; fn < 4; fn++)
                acc[fm][fn] = __builtin_amdgcn_mfma_f32_16x16x32_bf16(
                    af[fm], bfr[fn], acc[fm][fn], 0, 0, 0);
        __syncthreads();
    }

#pragma unroll
    for (int fm = 0; fm < 4; fm++) {
#pragma unroll
        for (int fn = 0; fn < 4; fn++) {
            int gcol = n0 + wc * 64 + fn * 16 + lrow;
            float bv = ldx(bias, gcol, b_f32);
#pragma unroll
            for (int r = 0; r < 4; r++) {
                int grow = m0 + wr * 64 + fm * 16 + quad * 4 + r;
                size_t cidx = c_off + (size_t)grow * N + gcol;
                float val = acc[fm][fn][r] + bv;
                if (c_f32) ((float*)C)[cidx] = val;
                else       ((unsigned short*)C)[cidx] = f2b(val);
            }
        }
    }
}

// ---------------------------------------------------------------------------
// Depthwise 3x3 (taps -2,-1,0) + gate, v3: chunked exchange.
// As v2, but the per-column barrier is replaced by one barrier per 8-column
// chunk: wave1 writes x1 (f32) into a double-buffered 8x256 LDS slab, wave2
// stashes its 8 v-results in regs (static idx under full unroll), and gates
// after the chunk barrier. 32 -> 4 barriers; waves decoupled within chunks.
// Grid (S, 4, nb), 192 threads.
// ---------------------------------------------------------------------------
__global__ __launch_bounds__(192) void conv3_gate(
    const unsigned short* __restrict__ U, size_t u_zs,
    const void* __restrict__ sfw, const void* __restrict__ sfb,
    unsigned short* __restrict__ Wb, unsigned short* __restrict__ X0, size_t o_zs,
    const int* __restrict__ flag)
{
    __shared__ __align__(16) float x1f[2][8][256];   // 16 KB double-buffered

    const int f32f = flag[0];
    const int i    = blockIdx.x;
    const int j0   = blockIdx.y * 32;
    const int tid  = threadIdx.x;
    const int wv   = tid >> 6;        // 0:x0  1:x1  2:v
    const int lane = tid & 63;
    const int ch0  = wv * 256 + lane * 4;   // first of this thread's 4 channels

    const unsigned short* Ub = U + (size_t)blockIdx.z * u_zs;
    unsigned short* Wbb = Wb + (size_t)blockIdx.z * o_zs;
    unsigned short* X0b = X0 + (size_t)blockIdx.z * o_zs;

    float wgt[3][3][4], bias[4];
#pragma unroll
    for (int c = 0; c < 4; c++) {
        int ch = ch0 + c;
        bias[c] = ldx(sfb, ch, f32f);
#pragma unroll
        for (int ki = 0; ki < 3; ki++)
#pragma unroll
            for (int kj = 0; kj < 3; kj++)
                wgt[ki][kj][c] = ldx(sfw, ch * 9 + ki * 3 + kj, f32f);
    }

    bool rok[3];
    const unsigned short* rp[3];
#pragma unroll
    for (int ki = 0; ki < 3; ki++) {
        int row = i + ki - 2;
        rok[ki] = (row >= 0);
        rp[ki]  = Ub + (size_t)(row * S_DIM) * 768 + ch0;
    }

    float win[3][3][4];
#define DLOAD(slot, col)                                                       \
    { _Pragma("unroll") for (int ki = 0; ki < 3; ki++) {                       \
        if (rok[ki] && (col) >= 0) {                                           \
            uint2 p = *(const uint2*)(rp[ki] + (size_t)(col) * 768);           \
            win[slot][ki][0] = b2f((unsigned short)p.x);                       \
            win[slot][ki][1] = b2f((unsigned short)(p.x >> 16));               \
            win[slot][ki][2] = b2f((unsigned short)p.y);                       \
            win[slot][ki][3] = b2f((unsigned short)(p.y >> 16));               \
        } else {                                                               \
            win[slot][ki][0] = 0.f; win[slot][ki][1] = 0.f;                    \
            win[slot][ki][2] = 0.f; win[slot][ki][3] = 0.f;                    \
        } } }

    DLOAD(0, j0 - 2)
    DLOAD(1, j0 - 1)

    uint2 nxt[3];
#pragma unroll
    for (int ki = 0; ki < 3; ki++) {
        uint2 p; p.x = 0u; p.y = 0u;
        if (rok[ki]) p = *(const uint2*)(rp[ki] + (size_t)j0 * 768);
        nxt[ki] = p;
    }

    float vb[8][4];   // wave2's v-results for the current chunk (static idx)

#pragma unroll
    for (int jj = 0; jj < 32; jj++) {
        const int j  = j0 + jj;
        const int sA = jj % 3, sB = (jj + 1) % 3, sC = (jj + 2) % 3;
        const int ck = jj >> 3;    // chunk 0..3
        const int sl = jj & 7;     // slot in chunk (compile-time)

#pragma unroll
        for (int ki = 0; ki < 3; ki++) {
            win[sC][ki][0] = b2f((unsigned short)nxt[ki].x);
            win[sC][ki][1] = b2f((unsigned short)(nxt[ki].x >> 16));
            win[sC][ki][2] = b2f((unsigned short)nxt[ki].y);
            win[sC][ki][3] = b2f((unsigned short)(nxt[ki].y >> 16));
        }
        {
            const int jn = j + 1;
            const bool jok = (jn < S_DIM);
#pragma unroll
            for (int ki = 0; ki < 3; ki++) {
                uint2 p; p.x = 0u; p.y = 0u;
                if (jok && rok[ki]) p = *(const uint2*)(rp[ki] + (size_t)jn * 768);
                nxt[ki] = p;
            }
        }

        float o[4];
#pragma unroll
        for (int c = 0; c < 4; c++) {
            float a = bias[c];
#pragma unroll
            for (int ki = 0; ki < 3; ki++)
                a += wgt[ki][0][c] * win[sA][ki][c]
                   + wgt[ki][1][c] * win[sB][ki][c]
                   + wgt[ki][2][c] * win[sC][ki][c];
            o[c] = a;
        }

        if (wv == 1) {
            float4 v4; v4.x = o[0]; v4.y = o[1]; v4.z = o[2]; v4.w = o[3];
            *(float4*)(&x1f[ck & 1][sl][lane * 4]) = v4;
        } else if (wv == 0) {
            const size_t oidx = (size_t)(i * S_DIM + j) * 256 + lane * 4;
            unsigned int lo = (unsigned int)f2b(o[0]) | ((unsigned int)f2b(o[1]) << 16);
            unsigned int hi = (unsigned int)f2b(o[2]) | ((unsigned int)f2b(o[3]) << 16);
            uint2 st; st.x = lo; st.y = hi;
            *(uint2*)(&X0b[oidx]) = st;
        } else {
#pragma unroll
            for (int c = 0; c < 4; c++) vb[sl][c] = o[c];
        }

        // shift window
#pragma unroll
        for (int cc = 0; cc < 3; cc++) { /* rotation via slot indices; no-op */ }

        if (sl == 7) {
            __syncthreads();
            if (wv == 2) {
#pragma unroll
                for (int s2 = 0; s2 < 8; s2++) {
                    float4 xp = *(const float4*)(&x1f[ck & 1][s2][lane * 4]);
                    float r0 = vb[s2][0] * xp.x;
                    float r1 = vb[s2][1] * xp.y;
                    float r2 = vb[s2][2] * xp.z;
                    float r3 = vb[s2][3] * xp.w;
                    const int jc = j0 + ck * 8 + s2;
                    const size_t oidx = (size_t)(i * S_DIM + jc) * 256 + lane * 4;
                    unsigned int lo = (unsigned int)f2b(r0) | ((unsigned int)f2b(r1) << 16);
                    unsigned int hi = (unsigned int)f2b(r2) | ((unsigned int)f2b(r3) << 16);
                    uint2 st; st.x = lo; st.y = hi;
                    *(uint2*)(&Wbb[oidx]) = st;
                }
            }
        }
    }
#undef DLOAD
}

// ---------------------------------------------------------------------------
// Causal conv along j, v8: r-block inner loop (round-8) + single-staging:
// grid (S, 1, nb); each block stages its 64KB panel ONCE and loops all 8
// output tiles (dynamic trip counts — I-cache safe). Staging traffic /4.
// ---------------------------------------------------------------------------
__global__ __launch_bounds__(256) void conv_j(
    const unsigned short* __restrict__ Wb, size_t zs,
    const float* __restrict__ hy,
    unsigned short* __restrict__ Aout)
{
    __shared__ unsigned short wl[S_DIM * 256];  // 64 KB, [j][d]
    const int i = blockIdx.x;
    const int tid = threadIdx.x;
    const size_t zoff = (size_t)blockIdx.z * zs;
    const size_t sbase = zoff + (size_t)(i * S_DIM) * 256;

    const uint4* gsrc = (const uint4*)(Wb + sbase);
    for (int c = tid; c < 4096; c += 256) ((uint4*)wl)[c] = gsrc[c];
    __syncthreads();

    const int d = tid;
    const float* hyd = hy + d;

    for (int jt = 0; jt < 8; jt++) {
        const int j0 = jt * 16;
        float acc[16];
#pragma unroll
        for (int jj = 0; jj < 16; jj++) acc[jj] = 0.f;

        // window ww[t] = W[j0+15-q0-t], t=0..23 (q0 = 0 initially)
        float ww[24];
#pragma unroll
        for (int t = 0; t < 24; t++) {
            int r = j0 + 15 - t;
            ww[t] = (r >= 0) ? b2f(wl[r * 256 + d]) : 0.f;
        }
        float hA[8], hB[8];
#pragma unroll
        for (int k = 0; k < 8; k++) hA[k] = hyd[k * 256];

        const int nbh = jt + 1;          // sub-block pairs
        for (int bb = 0; bb < nbh; bb++) {
            const int q0 = 16 * bb;
            const bool last = (bb + 1 == nbh);
            float wn[8];
            // ---- sub A: q = q0..q0+7 (sub B always follows) ----
#pragma unroll
            for (int k = 0; k < 8; k++) hB[k] = hyd[(q0 + 8 + k) * 256];
#pragma unroll
            for (int k = 0; k < 8; k++) {
                int r = j0 - q0 - 9 - k;
                wn[k] = (r >= 0) ? b2f(wl[r * 256 + d]) : 0.f;
            }
#pragma unroll
            for (int k = 0; k < 8; k++)
#pragma unroll
                for (int jj = 0; jj < 16; jj++)
                    acc[jj] += hA[k] * ww[15 - jj + k];
#pragma unroll
            for (int t = 0; t < 16; t++) ww[t] = ww[t + 8];
#pragma unroll
            for (int k = 0; k < 8; k++) ww[16 + k] = wn[k];
            // ---- sub B: q = q0+8..q0+15 ----
            if (!last) {
#pragma unroll
                for (int k = 0; k < 8; k++) hA[k] = hyd[(q0 + 16 + k) * 256];
#pragma unroll
                for (int k = 0; k < 8; k++) {
                    int r = j0 - q0 - 17 - k;
                    wn[k] = (r >= 0) ? b2f(wl[r * 256 + d]) : 0.f;
                }
            }
#pragma unroll
            for (int k = 0; k < 8; k++)
#pragma unroll
                for (int jj = 0; jj < 16; jj++)
                    acc[jj] += hB[k] * ww[15 - jj + k];
            if (!last) {
#pragma unroll
                for (int t = 0; t < 16; t++) ww[t] = ww[t + 8];
#pragma unroll
                for (int k = 0; k < 8; k++) ww[16 + k] = wn[k];
            }
        }
#pragma unroll
        for (int jj = 0; jj < 16; jj++)
            Aout[sbase + (size_t)(j0 + jj) * 256 + d] = f2b(acc[jj]);
    }
}

// ---------------------------------------------------------------------------
// Causal conv along i + epilogue, v8 (same single-staging + r-block).
// Grid (S, 1, nb).
// ---------------------------------------------------------------------------
__global__ __launch_bounds__(256) void conv_i(
    const unsigned short* __restrict__ Ain, size_t zs,
    const float* __restrict__ hx,
    const unsigned short* __restrict__ Wb,
    const unsigned short* __restrict__ X0,
    const void* __restrict__ fbias,
    unsigned short* __restrict__ Gout,
    const int* __restrict__ flag)
{
    __shared__ unsigned short al[S_DIM * 256];  // [i][d]
    const int f32f = flag[0];
    const int j = blockIdx.x;
    const int tid = threadIdx.x;
    const size_t zoff = (size_t)blockIdx.z * zs;

    for (int c = tid; c < 4096; c += 256) {
        int row = c >> 5;
        int off = c & 31;
        const uint4* gsrc = (const uint4*)(Ain + zoff + (size_t)(row * S_DIM + j) * 256) + off;
        ((uint4*)al)[c] = *gsrc;
    }
    __syncthreads();

    const int d = tid;
    const float* hxd = hx + d;
    const float fb = ldx(fbias, d, f32f);

    for (int it = 0; it < 8; it++) {
        const int i0 = it * 16;
        float acc[16];
#pragma unroll
        for (int ii = 0; ii < 16; ii++) acc[ii] = 0.f;

        float ww[24];
#pragma unroll
        for (int t = 0; t < 24; t++) {
            int r = i0 + 15 - t;
            ww[t] = (r >= 0) ? b2f(al[r * 256 + d]) : 0.f;
        }
        float hA[8], hB[8];
#pragma unroll
        for (int k = 0; k < 8; k++) hA[k] = hxd[k * 256];

        const int nbh = it + 1;
        for (int bb = 0; bb < nbh; bb++) {
            const int q0 = 16 * bb;
            const bool last = (bb + 1 == nbh);
            float wn[8];
            // ---- sub A ----
#pragma unroll
            for (int k = 0; k < 8; k++) hB[k] = hxd[(q0 + 8 + k) * 256];
#pragma unroll
            for (int k = 0; k < 8; k++) {
                int r = i0 - q0 - 9 - k;
                wn[k] = (r >= 0) ? b2f(al[r * 256 + d]) : 0.f;
            }
#pragma unroll
            for (int k = 0; k < 8; k++)
#pragma unroll
                for (int ii = 0; ii < 16; ii++)
                    acc[ii] += hA[k] * ww[15 - ii + k];
#pragma unroll
            for (int t = 0; t < 16; t++) ww[t] = ww[t + 8];
#pragma unroll
            for (int k = 0; k < 8; k++) ww[16 + k] = wn[k];
            // ---- sub B ----
            if (!last) {
#pragma unroll
                for (int k = 0; k < 8; k++) hA[k] = hxd[(q0 + 16 + k) * 256];
#pragma unroll
                for (int k = 0; k < 8; k++) {
                    int r = i0 - q0 - 17 - k;
                    wn[k] = (r >= 0) ? b2f(al[r * 256 + d]) : 0.f;
                }
            }
#pragma unroll
            for (int k = 0; k < 8; k++)
#pragma unroll
                for (int ii = 0; ii < 16; ii++)
                    acc[ii] += hB[k] * ww[15 - ii + k];
            if (!last) {
#pragma unroll
                for (int t = 0; t < 16; t++) ww[t] = ww[t + 8];
#pragma unroll
                for (int k = 0; k < 8; k++) ww[16 + k] = wn[k];
            }
        }
#pragma unroll
        for (int ii = 0; ii < 16; ii++) {
            int i = i0 + ii;
            size_t idx = zoff + (size_t)(i * S_DIM + j) * 256 + d;
            float wv  = b2f(Wb[idx]);
            float x0v = b2f(X0[idx]);
            float y = acc[ii] * (1.0f / 256.0f) + wv * fb;
            Gout[idx] = f2b(y * x0v);
        }
    }
}

// ---------------------------------------------------------------------------
extern "C" void kernel_launch(void* const* d_in, const int* in_sizes, int n_in,
                              void* d_out, int out_size, void* d_ws, size_t ws_size,
                              hipStream_t stream)
{
    const void* x     = d_in[0];
    const void* in_w  = d_in[1];
    const void* in_b  = d_in[2];
    const void* out_w = d_in[3];
    const void* out_b_= d_in[4];
    const void* sf_w  = d_in[5];
    const void* sf_b  = d_in[6];
    const void* freq  = d_in[7];
    const void* xw0 = d_in[8];  const void* xb0 = d_in[9];
    const void* xw1 = d_in[10]; const void* xb1 = d_in[11];
    const void* xw2 = d_in[12]; const void* xb2 = d_in[13];
    const void* xw3 = d_in[14];
    const void* yw0 = d_in[15]; const void* yb0 = d_in[16];
    const void* yw1 = d_in[17]; const void* yb1 = d_in[18];
    const void* yw2 = d_in[19]; const void* yb2 = d_in[20];
    const void* yw3 = d_in[21];
    const void* fbias = d_in[22];

    char* ws = (char*)d_ws;
    const size_t UZ  = (size_t)L_DIM * 768;   // elements per batch, u
    const size_t OZ  = (size_t)L_DIM * 256;   // elements per batch, 256-ch bufs

    // Fused (all-batch) layout: 168,558,608 B. Fallback per-batch: 42,729,488 B.
    const size_t need_fused = 168558608;
    bool fused = (ws_size >= need_fused);

    if (fused) {
        unsigned short* u_f  = (unsigned short*)(ws + 0);           // 100663296 B
        unsigned short* A_f  = (unsigned short*)(ws + 0);           //  33554432 B (alias)
        unsigned short* G_f  = (unsigned short*)(ws + 33554432);    //  33554432 B (alias)
        unsigned short* Wb_f = (unsigned short*)(ws + 100663296);   //  33554432 B
        unsigned short* X0_f = (unsigned short*)(ws + 134217728);   //  33554432 B
        // xb aliases Wb_f: dead until conv3_gate; lifetime = cast..gemm1 only
        unsigned short* xb_f = (unsigned short*)(ws + 100663296);
        float* hx            = (float*)(ws + 167772160);
        float* hy            = (float*)(ws + 167903232);
        unsigned short* tin  = (unsigned short*)(ws + 168034304);
        unsigned short* tout = (unsigned short*)(ws + 168427520);
        int* flag            = (int*)(ws + 168558592);

        sniff_dtype<<<1, 256, 0, stream>>>((const unsigned short*)x, flag);
        transpose_any<<<dim3(768), 256, 0, stream>>>(in_w, tin, 256, 768, flag);
        transpose_any<<<dim3(256), 256, 0, stream>>>(out_w, tout, 256, 256, flag);
        filter_mlp<<<dim3(S_DIM), 256, 0, stream>>>(freq, xw0, xb0, xw1, xb1, xw2, xb2, xw3, hx, flag);
        filter_mlp<<<dim3(S_DIM), 256, 0, stream>>>(freq, yw0, yb0, yw1, yb1, yw2, yb2, yw3, hy, flag);

        cast_to_bf16<<<dim3(2048), 256, 0, stream>>>(
            x, 0, xb_f, (size_t)B_DIM * L_DIM * 256, flag);
        gemm_bt16<<<dim3(512, 6), 256, 0, stream>>>(
            xb_f, tin, in_b, 1, u_f, 0, 0, B_DIM * L_DIM, 768, 256, flag);
        conv3_gate<<<dim3(S_DIM, 4, B_DIM), 192, 0, stream>>>(
            u_f, UZ, sf_w, sf_b, Wb_f, X0_f, OZ, flag);
        conv_j<<<dim3(S_DIM, 1, B_DIM), 256, 0, stream>>>(Wb_f, OZ, hy, A_f);
        conv_i<<<dim3(S_DIM, 1, B_DIM), 256, 0, stream>>>(
            A_f, OZ, hx, Wb_f, X0_f, fbias, G_f, flag);
        gemm_bt16<<<dim3(512, 2), 256, 0, stream>>>(
            G_f, tout, out_b_, 1, d_out, 0, 1, B_DIM * L_DIM, 256, 256, flag);
    } else {
        unsigned short* u_b  = (unsigned short*)(ws + 0);          // 25165824 B
        unsigned short* A_b  = (unsigned short*)(ws + 0);          // alias
        unsigned short* G_b  = (unsigned short*)(ws + 8388608);    // alias
        unsigned short* Wb_b = (unsigned short*)(ws + 25165824);
        unsigned short* X0_b = (unsigned short*)(ws + 33554432);
        unsigned short* xb_b = (unsigned short*)(ws + 25165824);   // alias Wb_b
        float* hx            = (float*)(ws + 41943040);
        float* hy            = (float*)(ws + 42074112);
        unsigned short* tin  = (unsigned short*)(ws + 42205184);
        unsigned short* tout = (unsigned short*)(ws + 42598400);
        int* flag            = (int*)(ws + 42729472);

        sniff_dtype<<<1, 256, 0, stream>>>((const unsigned short*)x, flag);
        transpose_any<<<dim3(768), 256, 0, stream>>>(in_w, tin, 256, 768, flag);
        transpose_any<<<dim3(256), 256, 0, stream>>>(out_w, tout, 256, 256, flag);
        filter_mlp<<<dim3(S_DIM), 256, 0, stream>>>(freq, xw0, xb0, xw1, xb1, xw2, xb2, xw3, hx, flag);
        filter_mlp<<<dim3(S_DIM), 256, 0, stream>>>(freq, yw0, yb0, yw1, yb1, yw2, yb2, yw3, hy, flag);

        for (int b = 0; b < B_DIM; b++) {
            size_t xoff = (size_t)b * OZ;
            cast_to_bf16<<<dim3(2048), 256, 0, stream>>>(
                x, xoff, xb_b, (size_t)L_DIM * 256, flag);
            gemm_bt16<<<dim3(128, 6), 256, 0, stream>>>(
                xb_b, tin, in_b, 1, u_b, 0, 0, L_DIM, 768, 256, flag);
            conv3_gate<<<dim3(S_DIM, 4, 1), 192, 0, stream>>>(
                u_b, 0, sf_w, sf_b, Wb_b, X0_b, 0, flag);
            conv_j<<<dim3(S_DIM, 1, 1), 256, 0, stream>>>(Wb_b, 0, hy, A_b);
            conv_i<<<dim3(S_DIM, 1, 1), 256, 0, stream>>>(
                A_b, 0, hx, Wb_b, X0_b, fbias, G_b, flag);
            gemm_bt16<<<dim3(128, 2), 256, 0, stream>>>(
                G_b, tout, out_b_, 1, d_out, xoff, 1, L_DIM, 256, 256, flag);
        }
    }
}

// Round 13
// 516.490 us; speedup vs baseline: 1.0205x; 1.0205x over previous
//
#include <hip/hip_runtime.h>
#include <hip/hip_bf16.h>

#define S_DIM 128
#define B_DIM 4
#define L_DIM (S_DIM * S_DIM)   // 16384 per batch

typedef __bf16 bf16x8 __attribute__((ext_vector_type(8)));
typedef float f32x4 __attribute__((ext_vector_type(4)));

__device__ __forceinline__ float b2f(unsigned short u) {
    union { unsigned int i; float f; } v;
    v.i = ((unsigned int)u) << 16;
    return v.f;
}
__device__ __forceinline__ unsigned short f2b(float f) {
    union { float f; unsigned int i; } v;
    v.f = f;
    unsigned int x = v.i;
    return (unsigned short)((x + 0x7FFFu + ((x >> 16) & 1u)) >> 16);
}
__device__ __forceinline__ float ldx(const void* p, size_t i, int f32) {
    return f32 ? ((const float*)p)[i] : b2f(((const unsigned short*)p)[i]);
}
// async global->LDS, 16B per lane; lds dest must be wave-uniform base
__device__ __forceinline__ void gload16(const unsigned short* g, unsigned short* l) {
    __builtin_amdgcn_global_load_lds(
        (const __attribute__((address_space(1))) unsigned int*)g,
        (__attribute__((address_space(3))) unsigned int*)l, 16, 0, 0);
}

// ---------------------------------------------------------------------------
__global__ __launch_bounds__(256) void sniff_dtype(const unsigned short* __restrict__ x,
                                                   int* __restrict__ flag) {
    __shared__ int cnt;
    if (threadIdx.x == 0) cnt = 0;
    __syncthreads();
    int c = 0;
    for (int i = threadIdx.x; i < 32768; i += 256) {
        unsigned int e = (x[i] >> 7) & 0xFFu;
        if (e >= 0x91u) c++;
    }
    atomicAdd(&cnt, c);
    __syncthreads();
    if (threadIdx.x == 0) flag[0] = (cnt > 64) ? 1 : 0;
}

// ---------------------------------------------------------------------------
__global__ void transpose_any(const void* __restrict__ src,
                              unsigned short* __restrict__ dst, int R, int C,
                              const int* __restrict__ flag) {
    const int f = flag[0];
    int idx = blockIdx.x * 256 + threadIdx.x;
    if (idx >= R * C) return;
    int r = idx / C, c = idx - r * C;
    dst[c * R + r] = f2b(ldx(src, idx, f));
}

// ---------------------------------------------------------------------------
// Cast x (f32 or bf16, per flag) to bf16. Vector 8-wide, grid-stride.
// ---------------------------------------------------------------------------
__global__ __launch_bounds__(256) void cast_to_bf16(
    const void* __restrict__ src, size_t s_off,
    unsigned short* __restrict__ dst, size_t n,
    const int* __restrict__ flag)
{
    const int f = flag[0];
    size_t idx = ((size_t)blockIdx.x * 256 + threadIdx.x) * 8;
    const size_t stride = (size_t)gridDim.x * 256 * 8;
    for (; idx < n; idx += stride) {
        if (f) {
            const float4* s4 = (const float4*)((const float*)src + s_off + idx);
            float4 a = s4[0], b = s4[1];
            uint4 w;
            w.x = (unsigned int)f2b(a.x) | ((unsigned int)f2b(a.y) << 16);
            w.y = (unsigned int)f2b(a.z) | ((unsigned int)f2b(a.w) << 16);
            w.z = (unsigned int)f2b(b.x) | ((unsigned int)f2b(b.y) << 16);
            w.w = (unsigned int)f2b(b.z) | ((unsigned int)f2b(b.w) << 16);
            *(uint4*)(dst + idx) = w;
        } else {
            *(uint4*)(dst + idx) =
                *(const uint4*)((const unsigned short*)src + s_off + idx);
        }
    }
}

// ---------------------------------------------------------------------------
// Implicit filter MLP: one block per s. out [s][d] f32 (includes decay).
// ---------------------------------------------------------------------------
__global__ __launch_bounds__(256) void filter_mlp(
    const void* __restrict__ freq,
    const void* __restrict__ w0, const void* __restrict__ b0,
    const void* __restrict__ w1, const void* __restrict__ b1,
    const void* __restrict__ w2, const void* __restrict__ b2,
    const void* __restrict__ w3,
    float* __restrict__ out, const int* __restrict__ flag)
{
    __shared__ float hs[64], gs[64];
    const int f32f = flag[0];
    const int s   = blockIdx.x;
    const int tid = threadIdx.x;
    const float t = (float)s / (float)(S_DIM - 1);
    const float ang = 1e-4f * 2.0f * 3.14159265358979323846f * ((float)s / (float)S_DIM);
    const float z0 = t, z1 = cosf(ang), z2 = -sinf(ang);

    if (tid < 64) {
        float fr = ldx(freq, tid, f32f);
        float a = z0 * ldx(w0, 0 * 64 + tid, f32f) + z1 * ldx(w0, 1 * 64 + tid, f32f) +
                  z2 * ldx(w0, 2 * 64 + tid, f32f) + ldx(b0, tid, f32f);
        hs[tid] = sinf(fr * a);
    }
    __syncthreads();
    if (tid < 64) {
        float fr = ldx(freq, tid, f32f);
        float a = ldx(b1, tid, f32f);
        for (int e = 0; e < 64; e++) a += hs[e] * ldx(w1, e * 64 + tid, f32f);
        gs[tid] = sinf(fr * a);
    }
    __syncthreads();
    if (tid < 64) {
        float fr = ldx(freq, tid, f32f);
        float a = ldx(b2, tid, f32f);
        for (int e = 0; e < 64; e++) a += gs[e] * ldx(w2, e * 64 + tid, f32f);
        hs[tid] = sinf(fr * a);
    }
    __syncthreads();
    {
        const float min_d = -3.0701134573253943f;   // ln(0.01)/1.5
        const float max_d = -15.350567286626971f;   // ln(0.01)/0.3
        float a = 0.f;
        for (int e = 0; e < 64; e++) a += hs[e] * ldx(w3, e * 256 + tid, f32f);
        float delta = min_d + (max_d - min_d) * ((float)tid / 255.0f);
        float dec = expf(-t * fabsf(delta));
        out[s * 256 + tid] = a * dec;
    }
}

// ---------------------------------------------------------------------------
// GEMM v2 (m97-style): C[M][N] = A[M][K]*BT[N][K]^T + bias[N], A/BT bf16.
// Linear LDS [128][32]; staging via global_load_lds width 16 (see r9 notes).
// ---------------------------------------------------------------------------
__global__ __launch_bounds__(256) void gemm_bt16(
    const unsigned short* __restrict__ A,
    const unsigned short* __restrict__ BT,
    const void* __restrict__ bias, int bias_ext,
    void* __restrict__ C, size_t c_off, int c_ext,
    int M, int N, int K, const int* __restrict__ flag)
{
    __shared__ __align__(16) unsigned short As[128 * 32];
    __shared__ __align__(16) unsigned short Bs[128 * 32];

    const int f     = flag[0];
    const int b_f32 = bias_ext && f;
    const int c_f32 = c_ext && f;

    const int tid  = threadIdx.x;
    const int m0   = blockIdx.x * 128;
    const int n0   = blockIdx.y * 128;
    const int wid  = tid >> 6;
    const int lane = tid & 63;
    const int lrow = lane & 15;
    const int quad = lane >> 4;
    const int wr   = wid >> 1, wc = wid & 1;

    const int srow = lane >> 2;
    const int scol = (lane & 3) * 8;

    f32x4 acc[4][4];
#pragma unroll
    for (int a = 0; a < 4; a++)
#pragma unroll
        for (int b = 0; b < 4; b++)
#pragma unroll
            for (int r = 0; r < 4; r++) acc[a][b][r] = 0.0f;

    for (int kc = 0; kc < K; kc += 32) {
#pragma unroll
        for (int c = 0; c < 2; c++) {
            const int ch  = wid * 2 + c;          // 0..7, wave-uniform
            const int row = ch * 16 + srow;
            gload16(A  + (size_t)(m0 + row) * K + kc + scol, &As[ch * 512]);
            gload16(BT + (size_t)(n0 + row) * K + kc + scol, &Bs[ch * 512]);
        }
        __syncthreads();

        bf16x8 af[4], bfr[4];
#pragma unroll
        for (int fm = 0; fm < 4; fm++)
            af[fm] = *(const bf16x8*)(&As[(wr * 64 + fm * 16 + lrow) * 32 + quad * 8]);
#pragma unroll
        for (int fn = 0; fn < 4; fn++)
            bfr[fn] = *(const bf16x8*)(&Bs[(wc * 64 + fn * 16 + lrow) * 32 + quad * 8]);
#pragma unroll
        for (int fm = 0; fm < 4; fm++)
#pragma unroll
            for (int fn = 0; fn < 4; fn++)
                acc[fm][fn] = __builtin_amdgcn_mfma_f32_16x16x32_bf16(
                    af[fm], bfr[fn], acc[fm][fn], 0, 0, 0);
        __syncthreads();
    }

#pragma unroll
    for (int fm = 0; fm < 4; fm++) {
#pragma unroll
        for (int fn = 0; fn < 4; fn++) {
            int gcol = n0 + wc * 64 + fn * 16 + lrow;
            float bv = ldx(bias, gcol, b_f32);
#pragma unroll
            for (int r = 0; r < 4; r++) {
                int grow = m0 + wr * 64 + fm * 16 + quad * 4 + r;
                size_t cidx = c_off + (size_t)grow * N + gcol;
                float val = acc[fm][fn][r] + bv;
                if (c_f32) ((float*)C)[cidx] = val;
                else       ((unsigned short*)C)[cidx] = f2b(val);
            }
        }
    }
}

// ---------------------------------------------------------------------------
// Depthwise 3x3 (taps -2,-1,0) + gate, v4: row-paired.
// v2 structure (per-column dbuf barrier exchange) but each block computes
// output rows {2r, 2r+1}: 4 input-row loads/column instead of 6 across the
// two v2 blocks it replaces; weights shared; 2 independent output rows = ILP.
// Grid (S/2, 4, nb), 192 threads (3 waves: x0 / x1 / v).
// ---------------------------------------------------------------------------
__global__ __launch_bounds__(192) void conv3_gate(
    const unsigned short* __restrict__ U, size_t u_zs,
    const void* __restrict__ sfw, const void* __restrict__ sfb,
    unsigned short* __restrict__ Wb, unsigned short* __restrict__ X0, size_t o_zs,
    const int* __restrict__ flag)
{
    __shared__ __align__(16) float x1f[2][2][256];   // dbuf x row x ch (4 KB)

    const int f32f = flag[0];
    const int r2   = blockIdx.x;          // output rows 2*r2, 2*r2+1
    const int i0   = 2 * r2;
    const int j0   = blockIdx.y * 32;
    const int tid  = threadIdx.x;
    const int wv   = tid >> 6;        // 0:x0  1:x1  2:v
    const int lane = tid & 63;
    const int ch0  = wv * 256 + lane * 4;   // first of this thread's 4 channels

    const unsigned short* Ub = U + (size_t)blockIdx.z * u_zs;
    unsigned short* Wbb = Wb + (size_t)blockIdx.z * o_zs;
    unsigned short* X0b = X0 + (size_t)blockIdx.z * o_zs;

    float wgt[3][3][4], bias[4];
#pragma unroll
    for (int c = 0; c < 4; c++) {
        int ch = ch0 + c;
        bias[c] = ldx(sfb, ch, f32f);
#pragma unroll
        for (int ki = 0; ki < 3; ki++)
#pragma unroll
            for (int kj = 0; kj < 3; kj++)
                wgt[ki][kj][c] = ldx(sfw, ch * 9 + ki * 3 + kj, f32f);
    }

    // 4 input rows: i0-2 .. i0+1
    bool rok[4];
    const unsigned short* rp[4];
#pragma unroll
    for (int ki = 0; ki < 4; ki++) {
        int row = i0 + ki - 2;
        rok[ki] = (row >= 0);   // row <= i0+1 <= 127 always
        rp[ki]  = Ub + (size_t)(row * S_DIM) * 768 + ch0;
    }

    float win[3][4][4];   // slot x inrow x ch
#define DLOAD(slot, col)                                                       \
    { _Pragma("unroll") for (int ki = 0; ki < 4; ki++) {                       \
        if (rok[ki] && (col) >= 0) {                                           \
            uint2 p = *(const uint2*)(rp[ki] + (size_t)(col) * 768);           \
            win[slot][ki][0] = b2f((unsigned short)p.x);                       \
            win[slot][ki][1] = b2f((unsigned short)(p.x >> 16));               \
            win[slot][ki][2] = b2f((unsigned short)p.y);                       \
            win[slot][ki][3] = b2f((unsigned short)(p.y >> 16));               \
        } else {                                                               \
            win[slot][ki][0] = 0.f; win[slot][ki][1] = 0.f;                    \
            win[slot][ki][2] = 0.f; win[slot][ki][3] = 0.f;                    \
        } } }

    DLOAD(0, j0 - 2)
    DLOAD(1, j0 - 1)

    uint2 nxt[4];
#pragma unroll
    for (int ki = 0; ki < 4; ki++) {
        uint2 p; p.x = 0u; p.y = 0u;
        if (rok[ki]) p = *(const uint2*)(rp[ki] + (size_t)j0 * 768);
        nxt[ki] = p;
    }

#pragma unroll
    for (int jj = 0; jj < 32; jj++) {
        const int j  = j0 + jj;
        const int sA = jj % 3, sB = (jj + 1) % 3, sC = (jj + 2) % 3;

#pragma unroll
        for (int ki = 0; ki < 4; ki++) {
            win[sC][ki][0] = b2f((unsigned short)nxt[ki].x);
            win[sC][ki][1] = b2f((unsigned short)(nxt[ki].x >> 16));
            win[sC][ki][2] = b2f((unsigned short)nxt[ki].y);
            win[sC][ki][3] = b2f((unsigned short)(nxt[ki].y >> 16));
        }
        {
            const int jn = j + 1;
            const bool jok = (jn < S_DIM);
#pragma unroll
            for (int ki = 0; ki < 4; ki++) {
                uint2 p; p.x = 0u; p.y = 0u;
                if (jok && rok[ki]) p = *(const uint2*)(rp[ki] + (size_t)jn * 768);
                nxt[ki] = p;
            }
        }

        float o0[4], o1[4];
#pragma unroll
        for (int c = 0; c < 4; c++) {
            float a0 = bias[c], a1 = bias[c];
#pragma unroll
            for (int ki = 0; ki < 3; ki++) {
                a0 += wgt[ki][0][c] * win[sA][ki][c]
                    + wgt[ki][1][c] * win[sB][ki][c]
                    + wgt[ki][2][c] * win[sC][ki][c];
                a1 += wgt[ki][0][c] * win[sA][ki + 1][c]
                    + wgt[ki][1][c] * win[sB][ki + 1][c]
                    + wgt[ki][2][c] * win[sC][ki + 1][c];
            }
            o0[c] = a0; o1[c] = a1;
        }

        const size_t oidx0 = (size_t)(i0 * S_DIM + j) * 256 + lane * 4;
        const size_t oidx1 = oidx0 + (size_t)S_DIM * 256;
        if (wv == 1) {
            float4 v0; v0.x = o0[0]; v0.y = o0[1]; v0.z = o0[2]; v0.w = o0[3];
            float4 v1; v1.x = o1[0]; v1.y = o1[1]; v1.z = o1[2]; v1.w = o1[3];
            *(float4*)(&x1f[jj & 1][0][lane * 4]) = v0;
            *(float4*)(&x1f[jj & 1][1][lane * 4]) = v1;
        } else if (wv == 0) {
            unsigned int lo0 = (unsigned int)f2b(o0[0]) | ((unsigned int)f2b(o0[1]) << 16);
            unsigned int hi0 = (unsigned int)f2b(o0[2]) | ((unsigned int)f2b(o0[3]) << 16);
            uint2 s0; s0.x = lo0; s0.y = hi0;
            *(uint2*)(&X0b[oidx0]) = s0;
            unsigned int lo1 = (unsigned int)f2b(o1[0]) | ((unsigned int)f2b(o1[1]) << 16);
            unsigned int hi1 = (unsigned int)f2b(o1[2]) | ((unsigned int)f2b(o1[3]) << 16);
            uint2 s1; s1.x = lo1; s1.y = hi1;
            *(uint2*)(&X0b[oidx1]) = s1;
        }
        __syncthreads();
        if (wv == 2) {
            float4 xp0 = *(const float4*)(&x1f[jj & 1][0][lane * 4]);
            float4 xp1 = *(const float4*)(&x1f[jj & 1][1][lane * 4]);
            float r0 = o0[0] * xp0.x, r1 = o0[1] * xp0.y;
            float r2 = o0[2] * xp0.z, r3 = o0[3] * xp0.w;
            unsigned int lo0 = (unsigned int)f2b(r0) | ((unsigned int)f2b(r1) << 16);
            unsigned int hi0 = (unsigned int)f2b(r2) | ((unsigned int)f2b(r3) << 16);
            uint2 s0; s0.x = lo0; s0.y = hi0;
            *(uint2*)(&Wbb[oidx0]) = s0;
            float q0 = o1[0] * xp1.x, q1 = o1[1] * xp1.y;
            float q2 = o1[2] * xp1.z, q3 = o1[3] * xp1.w;
            unsigned int lo1 = (unsigned int)f2b(q0) | ((unsigned int)f2b(q1) << 16);
            unsigned int hi1 = (unsigned int)f2b(q2) | ((unsigned int)f2b(q3) << 16);
            uint2 s1; s1.x = lo1; s1.y = hi1;
            *(uint2*)(&Wbb[oidx1]) = s1;
        }
    }
#undef DLOAD
}

// ---------------------------------------------------------------------------
// Causal conv along j, v8: r-block inner loop (round-8) + single-staging:
// grid (S, 1, nb); each block stages its 64KB panel ONCE and loops all 8
// output tiles (dynamic trip counts — I-cache safe). Staging traffic /4.
// ---------------------------------------------------------------------------
__global__ __launch_bounds__(256) void conv_j(
    const unsigned short* __restrict__ Wb, size_t zs,
    const float* __restrict__ hy,
    unsigned short* __restrict__ Aout)
{
    __shared__ unsigned short wl[S_DIM * 256];  // 64 KB, [j][d]
    const int i = blockIdx.x;
    const int tid = threadIdx.x;
    const size_t zoff = (size_t)blockIdx.z * zs;
    const size_t sbase = zoff + (size_t)(i * S_DIM) * 256;

    const uint4* gsrc = (const uint4*)(Wb + sbase);
    for (int c = tid; c < 4096; c += 256) ((uint4*)wl)[c] = gsrc[c];
    __syncthreads();

    const int d = tid;
    const float* hyd = hy + d;

    for (int jt = 0; jt < 8; jt++) {
        const int j0 = jt * 16;
        float acc[16];
#pragma unroll
        for (int jj = 0; jj < 16; jj++) acc[jj] = 0.f;

        // window ww[t] = W[j0+15-q0-t], t=0..23 (q0 = 0 initially)
        float ww[24];
#pragma unroll
        for (int t = 0; t < 24; t++) {
            int r = j0 + 15 - t;
            ww[t] = (r >= 0) ? b2f(wl[r * 256 + d]) : 0.f;
        }
        float hA[8], hB[8];
#pragma unroll
        for (int k = 0; k < 8; k++) hA[k] = hyd[k * 256];

        const int nbh = jt + 1;          // sub-block pairs
        for (int bb = 0; bb < nbh; bb++) {
            const int q0 = 16 * bb;
            const bool last = (bb + 1 == nbh);
            float wn[8];
            // ---- sub A: q = q0..q0+7 (sub B always follows) ----
#pragma unroll
            for (int k = 0; k < 8; k++) hB[k] = hyd[(q0 + 8 + k) * 256];
#pragma unroll
            for (int k = 0; k < 8; k++) {
                int r = j0 - q0 - 9 - k;
                wn[k] = (r >= 0) ? b2f(wl[r * 256 + d]) : 0.f;
            }
#pragma unroll
            for (int k = 0; k < 8; k++)
#pragma unroll
                for (int jj = 0; jj < 16; jj++)
                    acc[jj] += hA[k] * ww[15 - jj + k];
#pragma unroll
            for (int t = 0; t < 16; t++) ww[t] = ww[t + 8];
#pragma unroll
            for (int k = 0; k < 8; k++) ww[16 + k] = wn[k];
            // ---- sub B: q = q0+8..q0+15 ----
            if (!last) {
#pragma unroll
                for (int k = 0; k < 8; k++) hA[k] = hyd[(q0 + 16 + k) * 256];
#pragma unroll
                for (int k = 0; k < 8; k++) {
                    int r = j0 - q0 - 17 - k;
                    wn[k] = (r >= 0) ? b2f(wl[r * 256 + d]) : 0.f;
                }
            }
#pragma unroll
            for (int k = 0; k < 8; k++)
#pragma unroll
                for (int jj = 0; jj < 16; jj++)
                    acc[jj] += hB[k] * ww[15 - jj + k];
            if (!last) {
#pragma unroll
                for (int t = 0; t < 16; t++) ww[t] = ww[t + 8];
#pragma unroll
                for (int k = 0; k < 8; k++) ww[16 + k] = wn[k];
            }
        }
#pragma unroll
        for (int jj = 0; jj < 16; jj++)
            Aout[sbase + (size_t)(j0 + jj) * 256 + d] = f2b(acc[jj]);
    }
}

// ---------------------------------------------------------------------------
// Causal conv along i + epilogue, v8 (same single-staging + r-block).
// Grid (S, 1, nb).
// ---------------------------------------------------------------------------
__global__ __launch_bounds__(256) void conv_i(
    const unsigned short* __restrict__ Ain, size_t zs,
    const float* __restrict__ hx,
    const unsigned short* __restrict__ Wb,
    const unsigned short* __restrict__ X0,
    const void* __restrict__ fbias,
    unsigned short* __restrict__ Gout,
    const int* __restrict__ flag)
{
    __shared__ unsigned short al[S_DIM * 256];  // [i][d]
    const int f32f = flag[0];
    const int j = blockIdx.x;
    const int tid = threadIdx.x;
    const size_t zoff = (size_t)blockIdx.z * zs;

    for (int c = tid; c < 4096; c += 256) {
        int row = c >> 5;
        int off = c & 31;
        const uint4* gsrc = (const uint4*)(Ain + zoff + (size_t)(row * S_DIM + j) * 256) + off;
        ((uint4*)al)[c] = *gsrc;
    }
    __syncthreads();

    const int d = tid;
    const float* hxd = hx + d;
    const float fb = ldx(fbias, d, f32f);

    for (int it = 0; it < 8; it++) {
        const int i0 = it * 16;
        float acc[16];
#pragma unroll
        for (int ii = 0; ii < 16; ii++) acc[ii] = 0.f;

        float ww[24];
#pragma unroll
        for (int t = 0; t < 24; t++) {
            int r = i0 + 15 - t;
            ww[t] = (r >= 0) ? b2f(al[r * 256 + d]) : 0.f;
        }
        float hA[8], hB[8];
#pragma unroll
        for (int k = 0; k < 8; k++) hA[k] = hxd[k * 256];

        const int nbh = it + 1;
        for (int bb = 0; bb < nbh; bb++) {
            const int q0 = 16 * bb;
            const bool last = (bb + 1 == nbh);
            float wn[8];
            // ---- sub A ----
#pragma unroll
            for (int k = 0; k < 8; k++) hB[k] = hxd[(q0 + 8 + k) * 256];
#pragma unroll
            for (int k = 0; k < 8; k++) {
                int r = i0 - q0 - 9 - k;
                wn[k] = (r >= 0) ? b2f(al[r * 256 + d]) : 0.f;
            }
#pragma unroll
            for (int k = 0; k < 8; k++)
#pragma unroll
                for (int ii = 0; ii < 16; ii++)
                    acc[ii] += hA[k] * ww[15 - ii + k];
#pragma unroll
            for (int t = 0; t < 16; t++) ww[t] = ww[t + 8];
#pragma unroll
            for (int k = 0; k < 8; k++) ww[16 + k] = wn[k];
            // ---- sub B ----
            if (!last) {
#pragma unroll
                for (int k = 0; k < 8; k++) hA[k] = hxd[(q0 + 16 + k) * 256];
#pragma unroll
                for (int k = 0; k < 8; k++) {
                    int r = i0 - q0 - 17 - k;
                    wn[k] = (r >= 0) ? b2f(al[r * 256 + d]) : 0.f;
                }
            }
#pragma unroll
            for (int k = 0; k < 8; k++)
#pragma unroll
                for (int ii = 0; ii < 16; ii++)
                    acc[ii] += hB[k] * ww[15 - ii + k];
            if (!last) {
#pragma unroll
                for (int t = 0; t < 16; t++) ww[t] = ww[t + 8];
#pragma unroll
                for (int k = 0; k < 8; k++) ww[16 + k] = wn[k];
            }
        }
#pragma unroll
        for (int ii = 0; ii < 16; ii++) {
            int i = i0 + ii;
            size_t idx = zoff + (size_t)(i * S_DIM + j) * 256 + d;
            float wv  = b2f(Wb[idx]);
            float x0v = b2f(X0[idx]);
            float y = acc[ii] * (1.0f / 256.0f) + wv * fb;
            Gout[idx] = f2b(y * x0v);
        }
    }
}

// ---------------------------------------------------------------------------
extern "C" void kernel_launch(void* const* d_in, const int* in_sizes, int n_in,
                              void* d_out, int out_size, void* d_ws, size_t ws_size,
                              hipStream_t stream)
{
    const void* x     = d_in[0];
    const void* in_w  = d_in[1];
    const void* in_b  = d_in[2];
    const void* out_w = d_in[3];
    const void* out_b_= d_in[4];
    const void* sf_w  = d_in[5];
    const void* sf_b  = d_in[6];
    const void* freq  = d_in[7];
    const void* xw0 = d_in[8];  const void* xb0 = d_in[9];
    const void* xw1 = d_in[10]; const void* xb1 = d_in[11];
    const void* xw2 = d_in[12]; const void* xb2 = d_in[13];
    const void* xw3 = d_in[14];
    const void* yw0 = d_in[15]; const void* yb0 = d_in[16];
    const void* yw1 = d_in[17]; const void* yb1 = d_in[18];
    const void* yw2 = d_in[19]; const void* yb2 = d_in[20];
    const void* yw3 = d_in[21];
    const void* fbias = d_in[22];

    char* ws = (char*)d_ws;
    const size_t UZ  = (size_t)L_DIM * 768;   // elements per batch, u
    const size_t OZ  = (size_t)L_DIM * 256;   // elements per batch, 256-ch bufs

    // Fused (all-batch) layout: 168,558,608 B. Fallback per-batch: 42,729,488 B.
    const size_t need_fused = 168558608;
    bool fused = (ws_size >= need_fused);

    if (fused) {
        unsigned short* u_f  = (unsigned short*)(ws + 0);           // 100663296 B
        unsigned short* A_f  = (unsigned short*)(ws + 0);           //  33554432 B (alias)
        unsigned short* G_f  = (unsigned short*)(ws + 33554432);    //  33554432 B (alias)
        unsigned short* Wb_f = (unsigned short*)(ws + 100663296);   //  33554432 B
        unsigned short* X0_f = (unsigned short*)(ws + 134217728);   //  33554432 B
        // xb aliases Wb_f: dead until conv3_gate; lifetime = cast..gemm1 only
        unsigned short* xb_f = (unsigned short*)(ws + 100663296);
        float* hx            = (float*)(ws + 167772160);
        float* hy            = (float*)(ws + 167903232);
        unsigned short* tin  = (unsigned short*)(ws + 168034304);
        unsigned short* tout = (unsigned short*)(ws + 168427520);
        int* flag            = (int*)(ws + 168558592);

        sniff_dtype<<<1, 256, 0, stream>>>((const unsigned short*)x, flag);
        transpose_any<<<dim3(768), 256, 0, stream>>>(in_w, tin, 256, 768, flag);
        transpose_any<<<dim3(256), 256, 0, stream>>>(out_w, tout, 256, 256, flag);
        filter_mlp<<<dim3(S_DIM), 256, 0, stream>>>(freq, xw0, xb0, xw1, xb1, xw2, xb2, xw3, hx, flag);
        filter_mlp<<<dim3(S_DIM), 256, 0, stream>>>(freq, yw0, yb0, yw1, yb1, yw2, yb2, yw3, hy, flag);

        cast_to_bf16<<<dim3(2048), 256, 0, stream>>>(
            x, 0, xb_f, (size_t)B_DIM * L_DIM * 256, flag);
        gemm_bt16<<<dim3(512, 6), 256, 0, stream>>>(
            xb_f, tin, in_b, 1, u_f, 0, 0, B_DIM * L_DIM, 768, 256, flag);
        conv3_gate<<<dim3(S_DIM / 2, 4, B_DIM), 192, 0, stream>>>(
            u_f, UZ, sf_w, sf_b, Wb_f, X0_f, OZ, flag);
        conv_j<<<dim3(S_DIM, 1, B_DIM), 256, 0, stream>>>(Wb_f, OZ, hy, A_f);
        conv_i<<<dim3(S_DIM, 1, B_DIM), 256, 0, stream>>>(
            A_f, OZ, hx, Wb_f, X0_f, fbias, G_f, flag);
        gemm_bt16<<<dim3(512, 2), 256, 0, stream>>>(
            G_f, tout, out_b_, 1, d_out, 0, 1, B_DIM * L_DIM, 256, 256, flag);
    } else {
        unsigned short* u_b  = (unsigned short*)(ws + 0);          // 25165824 B
        unsigned short* A_b  = (unsigned short*)(ws + 0);          // alias
        unsigned short* G_b  = (unsigned short*)(ws + 8388608);    // alias
        unsigned short* Wb_b = (unsigned short*)(ws + 25165824);
        unsigned short* X0_b = (unsigned short*)(ws + 33554432);
        unsigned short* xb_b = (unsigned short*)(ws + 25165824);   // alias Wb_b
        float* hx            = (float*)(ws + 41943040);
        float* hy            = (float*)(ws + 42074112);
        unsigned short* tin  = (unsigned short*)(ws + 42205184);
        unsigned short* tout = (unsigned short*)(ws + 42598400);
        int* flag            = (int*)(ws + 42729472);

        sniff_dtype<<<1, 256, 0, stream>>>((const unsigned short*)x, flag);
        transpose_any<<<dim3(768), 256, 0, stream>>>(in_w, tin, 256, 768, flag);
        transpose_any<<<dim3(256), 256, 0, stream>>>(out_w, tout, 256, 256, flag);
        filter_mlp<<<dim3(S_DIM), 256, 0, stream>>>(freq, xw0, xb0, xw1, xb1, xw2, xb2, xw3, hx, flag);
        filter_mlp<<<dim3(S_DIM), 256, 0, stream>>>(freq, yw0, yb0, yw1, yb1, yw2, yb2, yw3, hy, flag);

        for (int b = 0; b < B_DIM; b++) {
            size_t xoff = (size_t)b * OZ;
            cast_to_bf16<<<dim3(2048), 256, 0, stream>>>(
                x, xoff, xb_b, (size_t)L_DIM * 256, flag);
            gemm_bt16<<<dim3(128, 6), 256, 0, stream>>>(
                xb_b, tin, in_b, 1, u_b, 0, 0, L_DIM, 768, 256, flag);
            conv3_gate<<<dim3(S_DIM / 2, 4, 1), 192, 0, stream>>>(
                u_b, 0, sf_w, sf_b, Wb_b, X0_b, 0, flag);
            conv_j<<<dim3(S_DIM, 1, 1), 256, 0, stream>>>(Wb_b, 0, hy, A_b);
            conv_i<<<dim3(S_DIM, 1, 1), 256, 0, stream>>>(
                A_b, 0, hx, Wb_b, X0_b, fbias, G_b, flag);
            gemm_bt16<<<dim3(128, 2), 256, 0, stream>>>(
                G_b, tout, out_b_, 1, d_out, xoff, 1, L_DIM, 256, 256, flag);
        }
    }
}